// Round 2
// baseline (224.998 us; speedup 1.0000x reference)
//
#include <hip/hip_runtime.h>

// GlobalLocalPool: B=16, T=4096, H=512, fp32 in/out.
// out[b, 0:H]   = sum_{t < len[b]}  x[b,t,:] / max(len[b],1)
// out[b, H:2H]  = sum_{mask[b,t]}   x[b,t,:] / max(popcount(mask[b]),1)
// (span-compaction in the reference is equivalent to a plain masked mean.)
// NOTE: harness passes the bool mask as int32 (one int per element).

constexpr int Bc = 16;
constexpr int Tc = 4096;
constexpr int Hc = 512;
constexpr int CHUNK  = 32;          // tokens per block
constexpr int NCHUNK = Tc / CHUNK;  // 128 chunk-blocks per batch row

// Kernel 1: partial sums over a token chunk, atomically accumulated into ws.
// Block = 128 threads; thread tid owns float4 slice h in [4*tid, 4*tid+4).
// Both predicates (t<len, mask[t]) are wave-uniform -> whole-wave load skip
// for tokens that contribute to neither sum (~25% of traffic saved).
__global__ __launch_bounds__(128) void glp_partial(
    const float* __restrict__ x,
    const int* __restrict__ lengths,
    const int* __restrict__ mask,   // int32 0/1
    float* __restrict__ gsum,       // [B][H]
    float* __restrict__ lsum,       // [B][H]
    int* __restrict__ cnt)          // [B]
{
    const int b   = blockIdx.x >> 7;     // / NCHUNK
    const int c   = blockIdx.x & (NCHUNK - 1);
    const int t0  = c * CHUNK;
    const int tid = threadIdx.x;         // 0..127
    const int len = lengths[b];

    const float4* __restrict__ xb =
        (const float4*)x + (size_t)b * Tc * (Hc / 4);
    const int* __restrict__ mb = mask + (size_t)b * Tc + t0;

    float4 g = make_float4(0.f, 0.f, 0.f, 0.f);
    float4 l = make_float4(0.f, 0.f, 0.f, 0.f);
    int mc = 0;

    #pragma unroll 4
    for (int i = 0; i < CHUNK; ++i) {
        const int t = t0 + i;
        const bool inlen = (t < len);
        const bool m     = (mb[i] != 0);
        if (inlen || m) {  // wave-uniform: skips the whole load when neither sum needs it
            float4 v = xb[(size_t)t * (Hc / 4) + tid];
            if (inlen) { g.x += v.x; g.y += v.y; g.z += v.z; g.w += v.w; }
            if (m)     { l.x += v.x; l.y += v.y; l.z += v.z; l.w += v.w; mc++; }
        }
    }

    float* gp = gsum + b * Hc + tid * 4;
    float* lp = lsum + b * Hc + tid * 4;
    atomicAdd(gp + 0, g.x); atomicAdd(gp + 1, g.y);
    atomicAdd(gp + 2, g.z); atomicAdd(gp + 3, g.w);
    atomicAdd(lp + 0, l.x); atomicAdd(lp + 1, l.y);
    atomicAdd(lp + 2, l.z); atomicAdd(lp + 3, l.w);
    if (tid == 0) atomicAdd(cnt + b, mc);   // mask is lane-uniform; tid0's count is exact
}

// Kernel 2: divide and emit [B, 2H].
__global__ __launch_bounds__(512) void glp_finalize(
    const float* __restrict__ gsum,
    const float* __restrict__ lsum,
    const int* __restrict__ cnt,
    const int* __restrict__ lengths,
    float* __restrict__ out)
{
    const int b = blockIdx.x;
    const int h = threadIdx.x;
    const float inv_len = 1.f / (float)max(lengths[b], 1);
    const float inv_cnt = 1.f / (float)max(cnt[b], 1);
    out[b * (2 * Hc) + h]      = gsum[b * Hc + h] * inv_len;
    out[b * (2 * Hc) + Hc + h] = lsum[b * Hc + h] * inv_cnt;
}

extern "C" void kernel_launch(void* const* d_in, const int* in_sizes, int n_in,
                              void* d_out, int out_size, void* d_ws, size_t ws_size,
                              hipStream_t stream) {
    const float* x     = (const float*)d_in[0];
    const int* lengths = (const int*)d_in[1];
    const int* mask    = (const int*)d_in[2];   // bool promoted to int32 by harness
    float* out = (float*)d_out;

    float* gsum = (float*)d_ws;
    float* lsum = gsum + Bc * Hc;
    int*   cnt  = (int*)(lsum + Bc * Hc);

    const size_t zero_bytes = (size_t)(2 * Bc * Hc) * sizeof(float) + Bc * sizeof(int);
    hipMemsetAsync(d_ws, 0, zero_bytes, stream);  // ws is poisoned 0xAA each call

    glp_partial<<<Bc * NCHUNK, 128, 0, stream>>>(x, lengths, mask, gsum, lsum, cnt);
    glp_finalize<<<Bc, Hc, 0, stream>>>(gsum, lsum, cnt, lengths, out);
}